// Round 13
// baseline (1467.446 us; speedup 1.0000x reference)
//
#include <hip/hip_runtime.h>
#include <math.h>

#define KK 10
#define NN 96
#define TT 40

#define HZf 10.0f
#define R0f 0.5f
#define R1f 4.0f
#define RSTEPf ((4.0f - 0.5f) / 6.0f)
#define TWO_PIf 6.2831853071795864769f
#define TSTEPf (6.2831853071795864769f / 6.0f)

typedef unsigned short u16;
typedef unsigned int u32;
typedef unsigned long long u64;
typedef float f32x4 __attribute__((ext_vector_type(4)));

__device__ __forceinline__ u16 f2bf(float f) {
    union { float f; unsigned u; } v; v.f = f;
    unsigned r = v.u + 0x7fffu + ((v.u >> 16) & 1u);
    return (u16)(r >> 16);
}
__device__ __forceinline__ float bflo(u32 u) {
    union { unsigned u; float f; } v; v.u = u << 16; return v.f;
}
__device__ __forceinline__ float bfhi(u32 u) {
    union { unsigned u; float f; } v; v.u = u & 0xffff0000u; return v.f;
}
__device__ __forceinline__ float bf2f(u16 h) {
    union { unsigned u; float f; } v; v.u = ((unsigned)h) << 16; return v.f;
}
__device__ __forceinline__ float sigmoidf_(float x) { return 1.0f / (1.0f + expf(-x)); }

// ---------------- conv1 tiled (proven round 12) ----------------
__global__ __launch_bounds__(256) void conv1_t(const float* __restrict__ img,
                                               const float* __restrict__ w,
                                               const float* __restrict__ b,
                                               float* __restrict__ out) {
    __shared__ float sW[1600];
    __shared__ float sIn[1444];
    const int tid = threadIdx.x;
    const int bx = blockIdx.x % 10, by = blockIdx.x / 10;
    const int x0 = bx * 8, y0 = by * 8;
    for (int i = tid; i < 1600; i += 256) {
        int oc = i & 15, t2 = i >> 4, tap = t2 % 25, ic = t2 / 25;
        sW[i] = w[(oc * 4 + ic) * 25 + tap];
    }
    for (int i = tid; i < 1444; i += 256) {
        int ic = i / 361, rem = i % 361, r = rem / 19, c = rem % 19;
        int gy = 2 * y0 - 2 + r, gx = 2 * x0 - 2 + c;
        sIn[i] = (gy >= 0 && gy < 160 && gx >= 0 && gx < 160)
                     ? img[(ic * 160 + gy) * 160 + gx] : 0.f;
    }
    __syncthreads();
    const int pix = tid & 63, ocg = tid >> 6;
    const int px = pix & 7, py = pix >> 3;
    float acc[4];
#pragma unroll
    for (int j = 0; j < 4; ++j) acc[j] = b[ocg * 4 + j];
#pragma unroll
    for (int ic = 0; ic < 4; ++ic) {
        int ibase = ic * 361;
#pragma unroll
        for (int ky = 0; ky < 5; ++ky)
#pragma unroll
            for (int kx = 0; kx < 5; ++kx) {
                float iv = sIn[ibase + (2 * py + ky) * 19 + 2 * px + kx];
                f32x4 wv = *(const f32x4*)&sW[(ic * 25 + ky * 5 + kx) * 16 + ocg * 4];
#pragma unroll
                for (int j = 0; j < 4; ++j) acc[j] += iv * wv[j];
            }
    }
#pragma unroll
    for (int j = 0; j < 4; ++j)
        out[((ocg * 4 + j) * 80 + y0 + py) * 80 + x0 + px] = fmaxf(acc[j], 0.f);
}

// ---------------- conv2 tiled (proven round 12) ----------------
__global__ __launch_bounds__(256) void conv2_t(const float* __restrict__ in,
                                               const float* __restrict__ w,
                                               const float* __restrict__ b,
                                               float* __restrict__ out) {
    __shared__ float sW[12800];
    __shared__ float sIn[2304];
    const int tid = threadIdx.x;
    const int bx = blockIdx.x % 10, by = blockIdx.x / 10;
    const int x0 = bx * 8, y0 = by * 8;
    for (int i = tid; i < 12800; i += 256) {
        int oc = i & 31, t2 = i >> 5, tap = t2 % 25, ic = t2 / 25;
        sW[i] = w[(oc * 16 + ic) * 25 + tap];
    }
    for (int i = tid; i < 2304; i += 256) {
        int ic = i / 144, rem = i % 144, r = rem / 12, c = rem % 12;
        int gy = y0 - 2 + r, gx = x0 - 2 + c;
        sIn[i] = (gy >= 0 && gy < 80 && gx >= 0 && gx < 80)
                     ? in[(ic * 80 + gy) * 80 + gx] : 0.f;
    }
    __syncthreads();
    const int pix = tid & 63, ocg = tid >> 6;
    const int px = pix & 7, py = pix >> 3;
    float acc[8];
#pragma unroll
    for (int j = 0; j < 8; ++j) acc[j] = b[ocg * 8 + j];
    for (int ic = 0; ic < 16; ++ic) {
        int ibase = ic * 144;
#pragma unroll
        for (int ky = 0; ky < 5; ++ky)
#pragma unroll
            for (int kx = 0; kx < 5; ++kx) {
                float iv = sIn[ibase + (py + ky) * 12 + px + kx];
                int wb = (ic * 25 + ky * 5 + kx) * 32 + ocg * 8;
                f32x4 w0 = *(const f32x4*)&sW[wb];
                f32x4 w1 = *(const f32x4*)&sW[wb + 4];
#pragma unroll
                for (int j = 0; j < 4; ++j) { acc[j] += iv * w0[j]; acc[4 + j] += iv * w1[j]; }
            }
    }
#pragma unroll
    for (int j = 0; j < 8; ++j)
        out[((ocg * 8 + j) * 80 + y0 + py) * 80 + x0 + px] = fmaxf(acc[j], 0.f);
}

// ---------------- fused prologue: prep (222) + lhalf (9600) + bins (400) ----------------
__global__ __launch_bounds__(256) void pre_k(
    const float* __restrict__ scf, const float* __restrict__ wih,
    const float* __restrict__ whh, const float* __restrict__ bih,
    const float* __restrict__ bhh, const float* __restrict__ scfb,
    const float* __restrict__ hx, float* __restrict__ h0hist,
    u32* __restrict__ wscf_p, u32* __restrict__ Wr_p, u32* __restrict__ Wz_p,
    u32* __restrict__ Win_p, u32* __restrict__ Whn_p, float* __restrict__ bias5,
    const float* __restrict__ yp, const float* __restrict__ cur,
    const float* __restrict__ fmap, const float* __restrict__ vw,
    const float* __restrict__ vb, u16* __restrict__ lhalf_bf,
    u32* __restrict__ binc) {
    __shared__ float xs[96], ys[96];
    __shared__ int win_s[96 * 36];
    __shared__ int cnt_s[96 * 36];
    const int bid = blockIdx.x;
    if (bid < 222) {
        int idx = bid * 256 + threadIdx.x;
        if (idx < 41472) {
            int o = idx % 48, dp = (idx / 48) % 24, b = idx / 1152;
            float v0 = scf[o * 1728 + b * 48 + 2 * dp];
            float v1 = scf[o * 1728 + b * 48 + 2 * dp + 1];
            wscf_p[idx] = (u32)f2bf(v0) | ((u32)f2bf(v1) << 16);
        } else if (idx < 44928) {
            int j = idx - 41472, od = j % 48, dp = j / 48;
            int kk0 = 2 * dp, kk1 = 2 * dp + 1;
            float v0 = kk0 < 96 ? wih[od * 96 + kk0] : whh[od * 48 + kk0 - 96];
            float v1 = kk1 < 96 ? wih[od * 96 + kk1] : whh[od * 48 + kk1 - 96];
            Wr_p[j] = (u32)f2bf(v0) | ((u32)f2bf(v1) << 16);
        } else if (idx < 48384) {
            int j = idx - 44928, od = j % 48, dp = j / 48;
            int row = 48 + od, kk0 = 2 * dp, kk1 = 2 * dp + 1;
            float v0 = kk0 < 96 ? wih[row * 96 + kk0] : whh[row * 48 + kk0 - 96];
            float v1 = kk1 < 96 ? wih[row * 96 + kk1] : whh[row * 48 + kk1 - 96];
            Wz_p[j] = (u32)f2bf(v0) | ((u32)f2bf(v1) << 16);
        } else if (idx < 50688) {
            int j = idx - 48384, od = j % 48, dp = j / 48;
            int row = 96 + od;
            Win_p[j] = (u32)f2bf(wih[row * 96 + 2 * dp]) |
                       ((u32)f2bf(wih[row * 96 + 2 * dp + 1]) << 16);
        } else if (idx < 51840) {
            int j = idx - 50688, od = j % 48, dp = j / 48;
            int row = 96 + od;
            Whn_p[j] = (u32)f2bf(whh[row * 48 + 2 * dp]) |
                       ((u32)f2bf(whh[row * 48 + 2 * dp + 1]) << 16);
        } else if (idx < 52080) {
            int j = idx - 51840, od = j % 48, q = j / 48;
            float v;
            if (q == 0) v = bih[od] + bhh[od];
            else if (q == 1) v = bih[48 + od] + bhh[48 + od];
            else if (q == 2) v = bih[96 + od];
            else if (q == 3) v = bhh[96 + od];
            else v = scfb[od];
            bias5[j] = v;
        } else if (idx < 56688) {
            int j = idx - 52080;
            h0hist[j] = hx[j];
        }
    } else if (bid < 222 + 9600) {
        int item = (bid - 222) * 4 + (threadIdx.x >> 6);
        int lane = threadIdx.x & 63;
        int n = item % NN, k = (item / NN) % KK, t = item / (KK * NN);
        float lx = yp[((k * TT + t) * NN + n) * 2 + 0];
        float ly = yp[((k * TT + t) * NN + n) * 2 + 1];
        float px, py;
        if (t == 0) { px = cur[n * 2]; py = cur[n * 2 + 1]; }
        else { px = yp[((k * TT + t - 1) * NN + n) * 2]; py = yp[((k * TT + t - 1) * NN + n) * 2 + 1]; }
        float vx = (lx - px) * HZf, vy = (ly - py) * HZf;
        int ui = 40 - (int)ly, vi = 40 - (int)lx;
        ui = min(max(ui, 0), 79);
        vi = min(max(vi, 0), 79);
        int row = k * NN + n;
        u16* dst = lhalf_bf + ((size_t)t * 960 + row) * 48;
        if (lane < 32) {
            dst[lane] = f2bf(fmap[(lane * 80 + ui) * 80 + vi]);
        } else if (lane < 48) {
            int f = lane - 32;
            float a = vb[f] + vx * vw[f * 2 + 0] + vy * vw[f * 2 + 1];
            dst[lane] = f2bf(fmaxf(a, 0.0f));
        }
    } else {
        int tk = bid - 222 - 9600;  // t*10 + k
        int k = tk % KK, t = tk / KK;
        int tid = threadIdx.x;
        if (tid < 96) {
            xs[tid] = yp[((k * TT + t) * NN + tid) * 2 + 0];
            ys[tid] = yp[((k * TT + t) * NN + tid) * 2 + 1];
        }
        for (int i = tid; i < 96 * 36; i += 256) { win_s[i] = -1; cnt_s[i] = 0; }
        __syncthreads();
        for (int p = tid; p < 96 * 96; p += 256) {
            int i = p / 96, j = p % 96;
            if (i == j) continue;
            float dx = xs[j] - xs[i], dy = ys[j] - ys[i];
            float dist = sqrtf(dx * dx + dy * dy);
            if (dist < R0f || dist > R1f) continue;
            float dsafe = fmaxf(dist, 1e-10f);
            float cost = fminf(fmaxf(dx / dsafe, -1.0f), 1.0f);
            float ac = acosf(cost);
            float theta = (dy < 0.0f) ? (TWO_PIf - ac) : ac;
            int ub = (int)((dist - R0f) / RSTEPf); ub = min(max(ub, 0), 5);
            int vb = (int)(theta / TSTEPf);        vb = min(max(vb, 0), 5);
            int b = ub * 6 + vb;
            atomicAdd(&cnt_s[i * 36 + b], 1);
            atomicMax(&win_s[i * 36 + b], j);
        }
        __syncthreads();
        if (tid < 96) {
            u32 base = (u32)(t * 960 + k * 96 + tid) * 20u;
            u16* entg = (u16*)(binc + base + 2);
            u64 mask = 0ull;
            int ne = 0;
            for (int b = 0; b < 36; ++b) {
                int w = win_s[tid * 36 + b];
                if (w >= 0) {
                    mask |= 1ull << b;
                    entg[ne++] = (u16)((w << 8) | cnt_s[tid * 36 + b]);
                }
            }
            binc[base] = (u32)mask;
            binc[base + 1] = (u32)(mask >> 32);
        }
    }
}

// ---------------- helpers for the 2-step launch ----------------
// rhalf for one row (single wave, serial over occupied bins); hsrc = LDS f32 [96][48]
__device__ __forceinline__ float rhalf_row(const u32* __restrict__ bp,
                                           const float* __restrict__ hsrc,
                                           const u32* __restrict__ wscf_p, int lo,
                                           const float* __restrict__ biasL) {
    u64 mask = ((u64)bp[1] << 32) | (u64)bp[0];
    int ne = __popcll(mask);
    const u16* ent = (const u16*)(bp + 2);
    float acc = 0.f;
    u64 m2 = mask;
    for (int e = 0; e < ne; ++e) {
        int b = __ffsll((long long)m2) - 1;
        m2 &= m2 - 1;
        u32 en = ent[e];
        int win = (en >> 8) & 0xff;
        float cinv = 1.f / (float)(en & 0xff);
        const u32* wp = wscf_p + (b * 24) * 48 + lo;
        const float* xv = hsrc + win * 48;
        float a = 0.f;
#pragma unroll 8
        for (int dp = 0; dp < 24; ++dp) {
            u32 u = wp[dp * 48];
            a += bflo(u) * xv[2 * dp] + bfhi(u) * xv[2 * dp + 1];
        }
        acc += a * cinv;
    }
    return fmaxf(acc + biasL[192 + lo], 0.f);
}

// full GRU step for one row w at time t (single wave); hT/lhT are LDS for time t
__device__ __forceinline__ float stepA_row(
    int w, int t, int lo, const float* __restrict__ hT, const u16* __restrict__ lhT,
    const u32* __restrict__ binc, const u32* __restrict__ wscf_p,
    const u32* __restrict__ Wr_p, const u32* __restrict__ Wz_p,
    const u32* __restrict__ Win_p, const u32* __restrict__ Whn_p,
    const float* __restrict__ biasL) {
    const u32* bp = binc + (size_t)(t * 960 + w) * 20;
    float rh = rhalf_row(bp, hT, wscf_p, lo, biasL);
    float aR = 0.f, aZ = 0.f, aI = 0.f, aH = 0.f;
#pragma unroll 8
    for (int dp = 0; dp < 24; ++dp) {
        u32 xp = *(const u32*)&lhT[w * 48 + 2 * dp];
        float xlo = bflo(xp), xhi = bfhi(xp);
        u32 uR = Wr_p[dp * 48 + lo], uZ = Wz_p[dp * 48 + lo], uI = Win_p[dp * 48 + lo];
        aR += bflo(uR) * xlo + bfhi(uR) * xhi;
        aZ += bflo(uZ) * xlo + bfhi(uZ) * xhi;
        aI += bflo(uI) * xlo + bfhi(uI) * xhi;
    }
#pragma unroll 8
    for (int dp = 24; dp < 48; ++dp) {
        float xlo = __shfl(rh, 2 * dp - 48), xhi = __shfl(rh, 2 * dp - 47);
        u32 uR = Wr_p[dp * 48 + lo], uZ = Wz_p[dp * 48 + lo], uI = Win_p[dp * 48 + lo];
        aR += bflo(uR) * xlo + bfhi(uR) * xhi;
        aZ += bflo(uZ) * xlo + bfhi(uZ) * xhi;
        aI += bflo(uI) * xlo + bfhi(uI) * xhi;
    }
#pragma unroll 8
    for (int dp = 48; dp < 72; ++dp) {
        float xlo = hT[w * 48 + 2 * dp - 96], xhi = hT[w * 48 + 2 * dp - 95];
        u32 uR = Wr_p[dp * 48 + lo], uZ = Wz_p[dp * 48 + lo], uH = Whn_p[(dp - 48) * 48 + lo];
        aR += bflo(uR) * xlo + bfhi(uR) * xhi;
        aZ += bflo(uZ) * xlo + bfhi(uZ) * xhi;
        aH += bflo(uH) * xlo + bfhi(uH) * xhi;
    }
    float rr = sigmoidf_(aR + biasL[lo]);
    float zz = sigmoidf_(aZ + biasL[48 + lo]);
    float ng = tanhf(aI + biasL[96 + lo] + rr * (aH + biasL[144 + lo]));
    return (1.f - zz) * ng + zz * hT[w * 48 + lo];
}

// ---------------- 2-step launch ----------------
// blocks 0..95   : chain row r: t -> t+2 via local closure     (t <= TT-2)
// blocks 96..311 : rhalf_all[t] and [t+1] (recompute h(t+1))   (t <= TT-2)
// blocks 312..527: follower rows, 2 GRU steps s0=t-2, s0+1      (t >= 2)
__global__ __launch_bounds__(256) void step2_k(
    int t, float* __restrict__ h0hist, const u16* __restrict__ lhalf_bf,
    const u32* __restrict__ binc, const u32* __restrict__ wscf_p,
    const u32* __restrict__ Wr_p, const u32* __restrict__ Wz_p,
    const u32* __restrict__ Win_p, const u32* __restrict__ Whn_p,
    const float* __restrict__ bias5, const float* __restrict__ scw,
    float* __restrict__ score_acc, float* __restrict__ hfin,
    u16* __restrict__ rhalf_all, const float* __restrict__ hx,
    float* __restrict__ hf) {
    __shared__ char smem[52000];
    const int tid = threadIdx.x;
    const int wv = tid >> 6, lane = tid & 63;
    const int lo = lane < 48 ? lane : 47;
    const int bid = blockIdx.x;

    if (bid < 96) {
        if (t >= TT) return;
        float* hT = (float*)smem;                    // 4608 f
        float* h1 = (float*)(smem + 18432);          // 4608 f
        u16* lhT = (u16*)(smem + 36864);             // 4608 u16
        float* biasL = (float*)(smem + 46080);       // 240
        float* scwL = (float*)(smem + 47040);        // 48
        u32* sentB = (u32*)(smem + 47232);           // 20
        float* shxB = (float*)(smem + 47312);        // 144
        float* ps1 = (float*)(smem + 47888);         // 192
        float* ps2 = (float*)(smem + 48656);         // 768
        const int r = bid;
        for (int i = tid; i < 4608; i += 256) hT[i] = h0hist[(size_t)t * 4608 + i];
        {
            const u32* src = (const u32*)(lhalf_bf + (size_t)t * 960 * 48);
            for (int i = tid; i < 2304; i += 256) ((u32*)lhT)[i] = src[i];
        }
        if (tid < 240) biasL[tid] = bias5[tid];
        if (tid < 48) scwL[tid] = scw[tid];
        if (tid < 20) sentB[tid] = binc[(size_t)((t + 1) * 960 + r) * 20 + tid];
        __syncthreads();
        u64 maskB = ((u64)sentB[1] << 32) | (u64)sentB[0];
        int neB = __popcll(maskB);
        const u16* entB = (const u16*)(sentB + 2);
        int nS = neB + 1;
        float scoreA = 0.f;
        for (int idx = wv; idx < nS; idx += 4) {
            int w = (idx == 0) ? r : ((entB[idx - 1] >> 8) & 0xff);
            float hn = stepA_row(w, t, lo, hT, lhT, binc, wscf_p, Wr_p, Wz_p, Win_p,
                                 Whn_p, biasL);
            if (lane < 48) h1[w * 48 + lane] = hn;
            if (idx == 0) {  // w == r, wave 0
                scoreA = (lane < 48) ? hn * scwL[lane] : 0.f;
                if (lane < 48) h0hist[(size_t)(t + 1) * 4608 + r * 48 + lane] = hn;
            }
        }
        __syncthreads();
        // step B: row r, t+1 -> t+2, K-split over 4 waves
        if (tid < 48) {
            shxB[tid] = bf2f(lhalf_bf[((size_t)(t + 1) * 960 + r) * 48 + tid]);
            shxB[96 + tid] = h1[r * 48 + tid];
        }
        __syncthreads();
        float acc = 0.f;
        u64 m2 = maskB;
        for (int e = 0; e < neB; ++e) {
            int b = __ffsll((long long)m2) - 1;
            m2 &= m2 - 1;
            u32 en = entB[e];
            int win = (en >> 8) & 0xff;
            float cinv = 1.f / (float)(en & 0xff);
            const u32* wp = wscf_p + (b * 24 + wv * 6) * 48 + lo;
            const float* xv = h1 + win * 48 + wv * 12;
            float a = 0.f;
#pragma unroll
            for (int dp = 0; dp < 6; ++dp) {
                u32 u = wp[dp * 48];
                a += bflo(u) * xv[2 * dp] + bfhi(u) * xv[2 * dp + 1];
            }
            acc += a * cinv;
        }
        if (lane < 48) ps1[wv * 48 + lane] = acc;
        __syncthreads();
        if (wv == 0 && lane < 48) {
            float rh = ps1[lane] + ps1[48 + lane] + ps1[96 + lane] + ps1[144 + lane] +
                       biasL[192 + lane];
            shxB[48 + lane] = fmaxf(rh, 0.f);
        }
        __syncthreads();
        float aR = 0.f, aZ = 0.f, aI = 0.f, aH = 0.f;
        int dp0 = wv * 18;
#pragma unroll
        for (int i = 0; i < 18; ++i) {
            int dp = dp0 + i;
            u32 uR = Wr_p[dp * 48 + lo], uZ = Wz_p[dp * 48 + lo];
            float xlo = shxB[2 * dp], xhi = shxB[2 * dp + 1];
            aR += bflo(uR) * xlo + bfhi(uR) * xhi;
            aZ += bflo(uZ) * xlo + bfhi(uZ) * xhi;
            if (dp < 48) {
                u32 uI = Win_p[dp * 48 + lo];
                aI += bflo(uI) * xlo + bfhi(uI) * xhi;
            } else {
                u32 uH = Whn_p[(dp - 48) * 48 + lo];
                aH += bflo(uH) * xlo + bfhi(uH) * xhi;
            }
        }
        if (lane < 48) {
            ps2[(wv * 4 + 0) * 48 + lane] = aR;
            ps2[(wv * 4 + 1) * 48 + lane] = aZ;
            ps2[(wv * 4 + 2) * 48 + lane] = aI;
            ps2[(wv * 4 + 3) * 48 + lane] = aH;
        }
        __syncthreads();
        if (wv == 0) {
            float sv = scoreA;
            if (lane < 48) {
                float AR = 0.f, AZ = 0.f, AI = 0.f, AH = 0.f;
#pragma unroll
                for (int w2 = 0; w2 < 4; ++w2) {
                    AR += ps2[(w2 * 4 + 0) * 48 + lane];
                    AZ += ps2[(w2 * 4 + 1) * 48 + lane];
                    AI += ps2[(w2 * 4 + 2) * 48 + lane];
                    AH += ps2[(w2 * 4 + 3) * 48 + lane];
                }
                float hprev = shxB[96 + lane];
                float rr = sigmoidf_(AR + biasL[lane]);
                float zz = sigmoidf_(AZ + biasL[48 + lane]);
                float ng = tanhf(AI + biasL[96 + lane] + rr * (AH + biasL[144 + lane]));
                float hn = (1.0f - zz) * ng + zz * hprev;
                h0hist[(size_t)(t + 2) * 4608 + r * 48 + lane] = hn;
                if (t + 2 == TT) hfin[r * 48 + lane] = hn;
                sv += hn * scwL[lane];
            }
            for (int off = 32; off; off >>= 1) sv += __shfl_down(sv, off);
            if (lane == 0) score_acc[r] = (t == 0 ? 0.f : score_acc[r]) + sv;
        }
    } else if (bid < 312) {
        if (t >= TT) return;
        float* hT = (float*)smem;
        float* h1 = (float*)(smem + 18432);
        u16* lhT = (u16*)(smem + 36864);
        float* biasL = (float*)(smem + 46080);
        u32* umask = (u32*)(smem + 47040);  // 3 words
        for (int i = tid; i < 4608; i += 256) hT[i] = h0hist[(size_t)t * 4608 + i];
        {
            const u32* src = (const u32*)(lhalf_bf + (size_t)t * 960 * 48);
            for (int i = tid; i < 2304; i += 256) ((u32*)lhT)[i] = src[i];
        }
        if (tid < 240) biasL[tid] = bias5[tid];
        if (tid < 3) umask[tid] = 0;
        __syncthreads();
        const int fr = 96 + (bid - 96) * 4 + wv;
        const u32* bpB = binc + (size_t)((t + 1) * 960 + fr) * 20;
        u64 maskB = ((u64)bpB[1] << 32) | (u64)bpB[0];
        int neB = __popcll(maskB);
        const u16* entB = (const u16*)(bpB + 2);
        if (lane == 0) {
            for (int e = 0; e < neB; ++e) {
                int w = (entB[e] >> 8) & 0xff;
                atomicOr(&umask[w >> 5], 1u << (w & 31));
            }
        }
        __syncthreads();
        // distributed stepA over the union of needed chain rows
        {
            int idx = 0;
#pragma unroll
            for (int word = 0; word < 3; ++word) {
                u32 m = umask[word];
                while (m) {
                    int b = __ffs(m) - 1;
                    m &= m - 1;
                    int w = word * 32 + b;
                    if ((idx & 3) == wv) {
                        float hn = stepA_row(w, t, lo, hT, lhT, binc, wscf_p, Wr_p, Wz_p,
                                             Win_p, Whn_p, biasL);
                        if (lane < 48) h1[w * 48 + lane] = hn;
                    }
                    idx++;
                }
            }
        }
        __syncthreads();
        // rhalf(fr, t) from hT
        {
            const u32* bpA = binc + (size_t)(t * 960 + fr) * 20;
            float rh = rhalf_row(bpA, hT, wscf_p, lo, biasL);
            if (lane < 48)
                rhalf_all[((size_t)t * 864 + (fr - 96)) * 48 + lane] = f2bf(rh);
        }
        // rhalf(fr, t+1) from h1
        {
            float rh = rhalf_row(bpB, h1, wscf_p, lo, biasL);
            if (lane < 48)
                rhalf_all[((size_t)(t + 1) * 864 + (fr - 96)) * 48 + lane] = f2bf(rh);
        }
    } else {
        int s0 = t - 2;
        if (s0 < 0) return;
        u32* sWr = (u32*)smem;                        // 3456
        u32* sWz = (u32*)(smem + 13824);              // 3456
        u32* sWin = (u32*)(smem + 27648);             // 2304
        u32* sx = (u32*)(smem + 36864) + wv * 48;     // 4x48
        float* shh = (float*)(smem + 37632) + wv * 48;// 4x48
        for (int i = tid; i < 3456; i += 256) { sWr[i] = Wr_p[i]; sWz[i] = Wz_p[i]; }
        for (int i = tid; i < 2304; i += 256) sWin[i] = Win_p[i];
        u32 whn[24];
#pragma unroll
        for (int dp = 0; dp < 24; ++dp) whn[dp] = Whn_p[dp * 48 + lo];
        const int widx = (bid - 312) * 4 + wv;  // 0..863
        const int row = 96 + widx;
        float hreg = (s0 == 0) ? hx[(row % 96) * 48 + lo] : hf[widx * 48 + lo];
        const float bRb = bias5[lo], bZb = bias5[48 + lo], bIb = bias5[96 + lo],
                    bHb = bias5[144 + lo];
        const float swv = (lane < 48) ? scw[lane] : 0.f;
        float score = 0.f;
        for (int ss = s0; ss < s0 + 2; ++ss) {
            if (lane < 24) {
                sx[lane] = *(const u32*)(lhalf_bf + ((size_t)ss * 960 + row) * 48 + 2 * lane);
                sx[24 + lane] =
                    *(const u32*)(rhalf_all + ((size_t)ss * 864 + widx) * 48 + 2 * lane);
            }
            if (lane < 48) shh[lane] = hreg;
            __syncthreads();
            float aR = 0.f, aZ = 0.f, aI = 0.f, aH = 0.f;
#pragma unroll 8
            for (int dp = 0; dp < 48; ++dp) {
                u32 xp = sx[dp];
                float xlo = bflo(xp), xhi = bfhi(xp);
                u32 uR = sWr[dp * 48 + lo], uZ = sWz[dp * 48 + lo], uI = sWin[dp * 48 + lo];
                aR += bflo(uR) * xlo + bfhi(uR) * xhi;
                aZ += bflo(uZ) * xlo + bfhi(uZ) * xhi;
                aI += bflo(uI) * xlo + bfhi(uI) * xhi;
            }
#pragma unroll 8
            for (int dp = 48; dp < 72; ++dp) {
                float xlo = shh[2 * dp - 96], xhi = shh[2 * dp - 95];
                u32 uR = sWr[dp * 48 + lo], uZ = sWz[dp * 48 + lo], uH = whn[dp - 48];
                aR += bflo(uR) * xlo + bfhi(uR) * xhi;
                aZ += bflo(uZ) * xlo + bfhi(uZ) * xhi;
                aH += bflo(uH) * xlo + bfhi(uH) * xhi;
            }
            float rr = sigmoidf_(aR + bRb);
            float zz = sigmoidf_(aZ + bZb);
            float ng = tanhf(aI + bIb + rr * (aH + bHb));
            hreg = (1.0f - zz) * ng + zz * hreg;
            score += hreg * swv;
            __syncthreads();
        }
        if (lane < 48) {
            hf[widx * 48 + lane] = hreg;
            if (s0 + 1 == TT - 1) hfin[(size_t)row * 48 + lane] = hreg;
        }
        for (int off = 32; off; off >>= 1) score += __shfl_down(score, off);
        if (lane == 0) score_acc[row] = (s0 == 0 ? 0.f : score_acc[row]) + score;
    }
}

// ---------------- epilogue ----------------
__global__ void final_k(const float* __restrict__ hlast, const float* __restrict__ score_acc,
                        const float* __restrict__ dyw, const float* __restrict__ dyb,
                        const float* __restrict__ scoreb, float* __restrict__ out) {
    int row = blockIdx.x, lane = threadIdx.x;
    int n = row % 96, k = row / 96;
    __shared__ float sh_h[48];
    if (lane < 48) sh_h[lane] = hlast[row * 48 + lane];
    __syncthreads();
    if (lane < 80) {
        float a = dyb[lane];
#pragma unroll 8
        for (int d = 0; d < 48; d++) a += sh_h[d] * dyw[lane * 48 + d];
        a = fmaxf(a, 0.0f);
        int j = lane / 40, tt = lane % 40;
        out[((k * TT + tt) * NN + n) * 2 + j] = a;
    } else if (lane == 80) {
        out[76800 + row] = score_acc[row] + 40.0f * scoreb[0];
    }
}

extern "C" void kernel_launch(void* const* d_in, const int* in_sizes, int n_in,
                              void* d_out, int out_size, void* d_ws, size_t ws_size,
                              hipStream_t stream) {
    const float* hx  = (const float*)d_in[0];
    const float* cur = (const float*)d_in[1];
    const float* yp  = (const float*)d_in[2];
    const float* img = (const float*)d_in[3];
    const float* c1w = (const float*)d_in[4];
    const float* c1b = (const float*)d_in[5];
    const float* c2w = (const float*)d_in[6];
    const float* c2b = (const float*)d_in[7];
    const float* vw  = (const float*)d_in[8];
    const float* vb  = (const float*)d_in[9];
    const float* wih = (const float*)d_in[10];
    const float* whh = (const float*)d_in[11];
    const float* bih = (const float*)d_in[12];
    const float* bhh = (const float*)d_in[13];
    const float* scfw = (const float*)d_in[14];
    const float* scfb = (const float*)d_in[15];
    const float* scw  = (const float*)d_in[16];
    const float* scb  = (const float*)d_in[17];
    const float* dyw  = (const float*)d_in[18];
    const float* dyb  = (const float*)d_in[19];
    float* out = (float*)d_out;

    char* ws = (char*)d_ws;  // ws_size ~268MB; no aliasing needed
    float* fmap1    = (float*)(ws + 0);          //   409,600
    float* fmap     = (float*)(ws + 409600);     //   819,200 -> 1228800
    u32*   binc     = (u32*)(ws + 1228800);      // 3,072,000 -> 4300800
    u16*   rhalf_all= (u16*)(ws + 4300800);      // 3,317,760 -> 7618560
    u16*   lhalf_bf = (u16*)(ws + 7618560);      // 3,686,400 -> 11304960
    float* h0hist   = (float*)(ws + 11304960);   //   755,712 -> 12060672
    float* hfin     = (float*)(ws + 12060672);   //   184,320 -> 12244992
    float* score_acc= (float*)(ws + 12244992);   //     3,840 -> 12248832
    u32*   wscf_p   = (u32*)(ws + 12248832);     //   165,888 -> 12414720
    u32*   Wr_p     = (u32*)(ws + 12414720);     //    13,824 -> 12428544
    u32*   Wz_p     = (u32*)(ws + 12428544);     //    13,824 -> 12442368
    u32*   Win_p    = (u32*)(ws + 12442368);     //     9,216 -> 12451584
    u32*   Whn_p    = (u32*)(ws + 12451584);     //     4,608 -> 12456192
    float* bias5    = (float*)(ws + 12456192);   //       960 -> 12457152
    float* hf       = (float*)(ws + 12457152);   //   165,888 -> 12623040

    conv1_t<<<100, 256, 0, stream>>>(img, c1w, c1b, fmap1);
    conv2_t<<<100, 256, 0, stream>>>(fmap1, c2w, c2b, fmap);
    pre_k<<<222 + 9600 + 400, 256, 0, stream>>>(scfw, wih, whh, bih, bhh, scfb, hx,
                                                h0hist, wscf_p, Wr_p, Wz_p, Win_p, Whn_p,
                                                bias5, yp, cur, fmap, vw, vb, lhalf_bf,
                                                binc);

    for (int t = 0; t <= TT; t += 2) {
        step2_k<<<528, 256, 0, stream>>>(t, h0hist, lhalf_bf, binc, wscf_p, Wr_p, Wz_p,
                                         Win_p, Whn_p, bias5, scw, score_acc, hfin,
                                         rhalf_all, hx, hf);
    }
    final_k<<<960, 128, 0, stream>>>(hfin, score_acc, dyw, dyb, scb, out);
}

// Round 14
// 774.893 us; speedup vs baseline: 1.8937x; 1.8937x over previous
//
#include <hip/hip_runtime.h>
#include <math.h>

#define KK 10
#define NN 96
#define TT 40

#define HZf 10.0f
#define R0f 0.5f
#define R1f 4.0f
#define RSTEPf ((4.0f - 0.5f) / 6.0f)
#define TWO_PIf 6.2831853071795864769f
#define TSTEPf (6.2831853071795864769f / 6.0f)

typedef unsigned short u16;
typedef unsigned int u32;
typedef unsigned long long u64;
typedef float f32x4 __attribute__((ext_vector_type(4)));

__device__ __forceinline__ u16 f2bf(float f) {
    union { float f; unsigned u; } v; v.f = f;
    unsigned r = v.u + 0x7fffu + ((v.u >> 16) & 1u);
    return (u16)(r >> 16);
}
__device__ __forceinline__ float bflo(u32 u) {
    union { unsigned u; float f; } v; v.u = u << 16; return v.f;
}
__device__ __forceinline__ float bfhi(u32 u) {
    union { unsigned u; float f; } v; v.u = u & 0xffff0000u; return v.f;
}
__device__ __forceinline__ float bf2f(u16 h) {
    union { unsigned u; float f; } v; v.u = ((unsigned)h) << 16; return v.f;
}
__device__ __forceinline__ float sigmoidf_(float x) { return 1.0f / (1.0f + expf(-x)); }

// ---------------- conv1 tiled (proven) ----------------
__global__ __launch_bounds__(256) void conv1_t(const float* __restrict__ img,
                                               const float* __restrict__ w,
                                               const float* __restrict__ b,
                                               float* __restrict__ out) {
    __shared__ float sW[1600];
    __shared__ float sIn[1444];
    const int tid = threadIdx.x;
    const int bx = blockIdx.x % 10, by = blockIdx.x / 10;
    const int x0 = bx * 8, y0 = by * 8;
    for (int i = tid; i < 1600; i += 256) {
        int oc = i & 15, t2 = i >> 4, tap = t2 % 25, ic = t2 / 25;
        sW[i] = w[(oc * 4 + ic) * 25 + tap];
    }
    for (int i = tid; i < 1444; i += 256) {
        int ic = i / 361, rem = i % 361, r = rem / 19, c = rem % 19;
        int gy = 2 * y0 - 2 + r, gx = 2 * x0 - 2 + c;
        sIn[i] = (gy >= 0 && gy < 160 && gx >= 0 && gx < 160)
                     ? img[(ic * 160 + gy) * 160 + gx] : 0.f;
    }
    __syncthreads();
    const int pix = tid & 63, ocg = tid >> 6;
    const int px = pix & 7, py = pix >> 3;
    float acc[4];
#pragma unroll
    for (int j = 0; j < 4; ++j) acc[j] = b[ocg * 4 + j];
#pragma unroll
    for (int ic = 0; ic < 4; ++ic) {
        int ibase = ic * 361;
#pragma unroll
        for (int ky = 0; ky < 5; ++ky)
#pragma unroll
            for (int kx = 0; kx < 5; ++kx) {
                float iv = sIn[ibase + (2 * py + ky) * 19 + 2 * px + kx];
                f32x4 wv = *(const f32x4*)&sW[(ic * 25 + ky * 5 + kx) * 16 + ocg * 4];
#pragma unroll
                for (int j = 0; j < 4; ++j) acc[j] += iv * wv[j];
            }
    }
#pragma unroll
    for (int j = 0; j < 4; ++j)
        out[((ocg * 4 + j) * 80 + y0 + py) * 80 + x0 + px] = fmaxf(acc[j], 0.f);
}

// ---------------- conv2 tiled (proven) ----------------
__global__ __launch_bounds__(256) void conv2_t(const float* __restrict__ in,
                                               const float* __restrict__ w,
                                               const float* __restrict__ b,
                                               float* __restrict__ out) {
    __shared__ float sW[12800];
    __shared__ float sIn[2304];
    const int tid = threadIdx.x;
    const int bx = blockIdx.x % 10, by = blockIdx.x / 10;
    const int x0 = bx * 8, y0 = by * 8;
    for (int i = tid; i < 12800; i += 256) {
        int oc = i & 31, t2 = i >> 5, tap = t2 % 25, ic = t2 / 25;
        sW[i] = w[(oc * 16 + ic) * 25 + tap];
    }
    for (int i = tid; i < 2304; i += 256) {
        int ic = i / 144, rem = i % 144, r = rem / 12, c = rem % 12;
        int gy = y0 - 2 + r, gx = x0 - 2 + c;
        sIn[i] = (gy >= 0 && gy < 80 && gx >= 0 && gx < 80)
                     ? in[(ic * 80 + gy) * 80 + gx] : 0.f;
    }
    __syncthreads();
    const int pix = tid & 63, ocg = tid >> 6;
    const int px = pix & 7, py = pix >> 3;
    float acc[8];
#pragma unroll
    for (int j = 0; j < 8; ++j) acc[j] = b[ocg * 8 + j];
    for (int ic = 0; ic < 16; ++ic) {
        int ibase = ic * 144;
#pragma unroll
        for (int ky = 0; ky < 5; ++ky)
#pragma unroll
            for (int kx = 0; kx < 5; ++kx) {
                float iv = sIn[ibase + (py + ky) * 12 + px + kx];
                int wb = (ic * 25 + ky * 5 + kx) * 32 + ocg * 8;
                f32x4 w0 = *(const f32x4*)&sW[wb];
                f32x4 w1 = *(const f32x4*)&sW[wb + 4];
#pragma unroll
                for (int j = 0; j < 4; ++j) { acc[j] += iv * w0[j]; acc[4 + j] += iv * w1[j]; }
            }
    }
#pragma unroll
    for (int j = 0; j < 8; ++j)
        out[((ocg * 8 + j) * 80 + y0 + py) * 80 + x0 + px] = fmaxf(acc[j], 0.f);
}

// ---------------- fused prologue (proven round 13) ----------------
__global__ __launch_bounds__(256) void pre_k(
    const float* __restrict__ scf, const float* __restrict__ wih,
    const float* __restrict__ whh, const float* __restrict__ bih,
    const float* __restrict__ bhh, const float* __restrict__ scfb,
    const float* __restrict__ hx, float* __restrict__ h0hist,
    u32* __restrict__ wscf_p, u32* __restrict__ Wr_p, u32* __restrict__ Wz_p,
    u32* __restrict__ Win_p, u32* __restrict__ Whn_p, float* __restrict__ bias5,
    const float* __restrict__ yp, const float* __restrict__ cur,
    const float* __restrict__ fmap, const float* __restrict__ vw,
    const float* __restrict__ vb, u16* __restrict__ lhalf_bf,
    u32* __restrict__ binc) {
    __shared__ float xs[96], ys[96];
    __shared__ int win_s[96 * 36];
    __shared__ int cnt_s[96 * 36];
    const int bid = blockIdx.x;
    if (bid < 222) {
        int idx = bid * 256 + threadIdx.x;
        if (idx < 41472) {
            int o = idx % 48, dp = (idx / 48) % 24, b = idx / 1152;
            float v0 = scf[o * 1728 + b * 48 + 2 * dp];
            float v1 = scf[o * 1728 + b * 48 + 2 * dp + 1];
            wscf_p[idx] = (u32)f2bf(v0) | ((u32)f2bf(v1) << 16);
        } else if (idx < 44928) {
            int j = idx - 41472, od = j % 48, dp = j / 48;
            int kk0 = 2 * dp, kk1 = 2 * dp + 1;
            float v0 = kk0 < 96 ? wih[od * 96 + kk0] : whh[od * 48 + kk0 - 96];
            float v1 = kk1 < 96 ? wih[od * 96 + kk1] : whh[od * 48 + kk1 - 96];
            Wr_p[j] = (u32)f2bf(v0) | ((u32)f2bf(v1) << 16);
        } else if (idx < 48384) {
            int j = idx - 44928, od = j % 48, dp = j / 48;
            int row = 48 + od, kk0 = 2 * dp, kk1 = 2 * dp + 1;
            float v0 = kk0 < 96 ? wih[row * 96 + kk0] : whh[row * 48 + kk0 - 96];
            float v1 = kk1 < 96 ? wih[row * 96 + kk1] : whh[row * 48 + kk1 - 96];
            Wz_p[j] = (u32)f2bf(v0) | ((u32)f2bf(v1) << 16);
        } else if (idx < 50688) {
            int j = idx - 48384, od = j % 48, dp = j / 48;
            int row = 96 + od;
            Win_p[j] = (u32)f2bf(wih[row * 96 + 2 * dp]) |
                       ((u32)f2bf(wih[row * 96 + 2 * dp + 1]) << 16);
        } else if (idx < 51840) {
            int j = idx - 50688, od = j % 48, dp = j / 48;
            int row = 96 + od;
            Whn_p[j] = (u32)f2bf(whh[row * 48 + 2 * dp]) |
                       ((u32)f2bf(whh[row * 48 + 2 * dp + 1]) << 16);
        } else if (idx < 52080) {
            int j = idx - 51840, od = j % 48, q = j / 48;
            float v;
            if (q == 0) v = bih[od] + bhh[od];
            else if (q == 1) v = bih[48 + od] + bhh[48 + od];
            else if (q == 2) v = bih[96 + od];
            else if (q == 3) v = bhh[96 + od];
            else v = scfb[od];
            bias5[j] = v;
        } else if (idx < 56688) {
            int j = idx - 52080;
            h0hist[j] = hx[j];
        }
    } else if (bid < 222 + 9600) {
        int item = (bid - 222) * 4 + (threadIdx.x >> 6);
        int lane = threadIdx.x & 63;
        int n = item % NN, k = (item / NN) % KK, t = item / (KK * NN);
        float lx = yp[((k * TT + t) * NN + n) * 2 + 0];
        float ly = yp[((k * TT + t) * NN + n) * 2 + 1];
        float px, py;
        if (t == 0) { px = cur[n * 2]; py = cur[n * 2 + 1]; }
        else { px = yp[((k * TT + t - 1) * NN + n) * 2]; py = yp[((k * TT + t - 1) * NN + n) * 2 + 1]; }
        float vx = (lx - px) * HZf, vy = (ly - py) * HZf;
        int ui = 40 - (int)ly, vi = 40 - (int)lx;
        ui = min(max(ui, 0), 79);
        vi = min(max(vi, 0), 79);
        int row = k * NN + n;
        u16* dst = lhalf_bf + ((size_t)t * 960 + row) * 48;
        if (lane < 32) {
            dst[lane] = f2bf(fmap[(lane * 80 + ui) * 80 + vi]);
        } else if (lane < 48) {
            int f = lane - 32;
            float a = vb[f] + vx * vw[f * 2 + 0] + vy * vw[f * 2 + 1];
            dst[lane] = f2bf(fmaxf(a, 0.0f));
        }
    } else {
        int tk = bid - 222 - 9600;  // t*10 + k
        int k = tk % KK, t = tk / KK;
        int tid = threadIdx.x;
        if (tid < 96) {
            xs[tid] = yp[((k * TT + t) * NN + tid) * 2 + 0];
            ys[tid] = yp[((k * TT + t) * NN + tid) * 2 + 1];
        }
        for (int i = tid; i < 96 * 36; i += 256) { win_s[i] = -1; cnt_s[i] = 0; }
        __syncthreads();
        for (int p = tid; p < 96 * 96; p += 256) {
            int i = p / 96, j = p % 96;
            if (i == j) continue;
            float dx = xs[j] - xs[i], dy = ys[j] - ys[i];
            float dist = sqrtf(dx * dx + dy * dy);
            if (dist < R0f || dist > R1f) continue;
            float dsafe = fmaxf(dist, 1e-10f);
            float cost = fminf(fmaxf(dx / dsafe, -1.0f), 1.0f);
            float ac = acosf(cost);
            float theta = (dy < 0.0f) ? (TWO_PIf - ac) : ac;
            int ub = (int)((dist - R0f) / RSTEPf); ub = min(max(ub, 0), 5);
            int vb = (int)(theta / TSTEPf);        vb = min(max(vb, 0), 5);
            int b = ub * 6 + vb;
            atomicAdd(&cnt_s[i * 36 + b], 1);
            atomicMax(&win_s[i * 36 + b], j);
        }
        __syncthreads();
        if (tid < 96) {
            u32 base = (u32)(t * 960 + k * 96 + tid) * 20u;
            u16* entg = (u16*)(binc + base + 2);
            u64 mask = 0ull;
            int ne = 0;
            for (int b = 0; b < 36; ++b) {
                int w = win_s[tid * 36 + b];
                if (w >= 0) {
                    mask |= 1ull << b;
                    entg[ne++] = (u16)((w << 8) | cnt_s[tid * 36 + b]);
                }
            }
            binc[base] = (u32)mask;
            binc[base + 1] = (u32)(mask >> 32);
        }
    }
}

// ---------------- helpers (proven round 13) ----------------
__device__ __forceinline__ float rhalf_row(const u32* __restrict__ bp,
                                           const float* __restrict__ hsrc,
                                           const u32* __restrict__ wscf_p, int lo,
                                           const float* __restrict__ biasL) {
    u64 mask = ((u64)bp[1] << 32) | (u64)bp[0];
    int ne = __popcll(mask);
    const u16* ent = (const u16*)(bp + 2);
    float acc = 0.f;
    u64 m2 = mask;
    for (int e = 0; e < ne; ++e) {
        int b = __ffsll((long long)m2) - 1;
        m2 &= m2 - 1;
        u32 en = ent[e];
        int win = (en >> 8) & 0xff;
        float cinv = 1.f / (float)(en & 0xff);
        const u32* wp = wscf_p + (b * 24) * 48 + lo;
        const float* xv = hsrc + win * 48;
        float a = 0.f;
#pragma unroll 8
        for (int dp = 0; dp < 24; ++dp) {
            u32 u = wp[dp * 48];
            a += bflo(u) * xv[2 * dp] + bfhi(u) * xv[2 * dp + 1];
        }
        acc += a * cinv;
    }
    return fmaxf(acc + biasL[192 + lo], 0.f);
}

__device__ __forceinline__ float stepA_row(
    int w, int t, int lo, const float* __restrict__ hT, const u16* __restrict__ lhT,
    const u32* __restrict__ binc, const u32* __restrict__ wscf_p,
    const u32* __restrict__ Wr_p, const u32* __restrict__ Wz_p,
    const u32* __restrict__ Win_p, const u32* __restrict__ Whn_p,
    const float* __restrict__ biasL) {
    const u32* bp = binc + (size_t)(t * 960 + w) * 20;
    float rh = rhalf_row(bp, hT, wscf_p, lo, biasL);
    float aR = 0.f, aZ = 0.f, aI = 0.f, aH = 0.f;
#pragma unroll 8
    for (int dp = 0; dp < 24; ++dp) {
        u32 xp = *(const u32*)&lhT[w * 48 + 2 * dp];
        float xlo = bflo(xp), xhi = bfhi(xp);
        u32 uR = Wr_p[dp * 48 + lo], uZ = Wz_p[dp * 48 + lo], uI = Win_p[dp * 48 + lo];
        aR += bflo(uR) * xlo + bfhi(uR) * xhi;
        aZ += bflo(uZ) * xlo + bfhi(uZ) * xhi;
        aI += bflo(uI) * xlo + bfhi(uI) * xhi;
    }
#pragma unroll 8
    for (int dp = 24; dp < 48; ++dp) {
        float xlo = __shfl(rh, 2 * dp - 48), xhi = __shfl(rh, 2 * dp - 47);
        u32 uR = Wr_p[dp * 48 + lo], uZ = Wz_p[dp * 48 + lo], uI = Win_p[dp * 48 + lo];
        aR += bflo(uR) * xlo + bfhi(uR) * xhi;
        aZ += bflo(uZ) * xlo + bfhi(uZ) * xhi;
        aI += bflo(uI) * xlo + bfhi(uI) * xhi;
    }
#pragma unroll 8
    for (int dp = 48; dp < 72; ++dp) {
        float xlo = hT[w * 48 + 2 * dp - 96], xhi = hT[w * 48 + 2 * dp - 95];
        u32 uR = Wr_p[dp * 48 + lo], uZ = Wz_p[dp * 48 + lo], uH = Whn_p[(dp - 48) * 48 + lo];
        aR += bflo(uR) * xlo + bfhi(uR) * xhi;
        aZ += bflo(uZ) * xlo + bfhi(uZ) * xhi;
        aH += bflo(uH) * xlo + bfhi(uH) * xhi;
    }
    float rr = sigmoidf_(aR + biasL[lo]);
    float zz = sigmoidf_(aZ + biasL[48 + lo]);
    float ng = tanhf(aI + biasL[96 + lo] + rr * (aH + biasL[144 + lo]));
    return (1.f - zz) * ng + zz * hT[w * 48 + lo];
}

// ---------------- 2-step pipelined launch ----------------
// t = 2i. blocks 0..95: chain t->t+2 (closure recompute, t<=38)
//         blocks 96..311: rhalf_all[t-1] (from h0hist[t-1]) and [t] (from h0hist[t])
//         blocks 312..527: followers steps t-4, t-3
__global__ __launch_bounds__(256) void step2_k(
    int t, float* __restrict__ h0hist, const u16* __restrict__ lhalf_bf,
    const u32* __restrict__ binc, const u32* __restrict__ wscf_p,
    const u32* __restrict__ Wr_p, const u32* __restrict__ Wz_p,
    const u32* __restrict__ Win_p, const u32* __restrict__ Whn_p,
    const float* __restrict__ bias5, const float* __restrict__ scw,
    float* __restrict__ score_acc, float* __restrict__ hfin,
    u16* __restrict__ rhalf_all, const float* __restrict__ hx,
    float* __restrict__ hf) {
    __shared__ char smem[52000];
    const int tid = threadIdx.x;
    const int wv = tid >> 6, lane = tid & 63;
    const int lo = lane < 48 ? lane : 47;
    const int bid = blockIdx.x;

    if (bid < 96) {
        if (t >= TT) return;
        float* hT = (float*)smem;                    // 4608 f
        float* h1 = (float*)(smem + 18432);          // 4608 f
        u16* lhT = (u16*)(smem + 36864);             // 4608 u16
        float* biasL = (float*)(smem + 46080);       // 240
        float* scwL = (float*)(smem + 47040);        // 48
        u32* sentB = (u32*)(smem + 47232);           // 20
        float* shxB = (float*)(smem + 47312);        // 144
        float* ps1 = (float*)(smem + 47888);         // 192
        float* ps2 = (float*)(smem + 48656);         // 768
        const int r = bid;
        for (int i = tid; i < 4608; i += 256) hT[i] = h0hist[(size_t)t * 4608 + i];
        {
            const u32* src = (const u32*)(lhalf_bf + (size_t)t * 960 * 48);
            for (int i = tid; i < 2304; i += 256) ((u32*)lhT)[i] = src[i];
        }
        if (tid < 240) biasL[tid] = bias5[tid];
        if (tid < 48) scwL[tid] = scw[tid];
        if (tid < 20) sentB[tid] = binc[(size_t)((t + 1) * 960 + r) * 20 + tid];
        __syncthreads();
        u64 maskB = ((u64)sentB[1] << 32) | (u64)sentB[0];
        int neB = __popcll(maskB);
        const u16* entB = (const u16*)(sentB + 2);
        int nS = neB + 1;
        float scoreA = 0.f;
        for (int idx = wv; idx < nS; idx += 4) {
            int w = (idx == 0) ? r : ((entB[idx - 1] >> 8) & 0xff);
            float hn = stepA_row(w, t, lo, hT, lhT, binc, wscf_p, Wr_p, Wz_p, Win_p,
                                 Whn_p, biasL);
            if (lane < 48) h1[w * 48 + lane] = hn;
            if (idx == 0) {
                scoreA = (lane < 48) ? hn * scwL[lane] : 0.f;
                if (lane < 48) h0hist[(size_t)(t + 1) * 4608 + r * 48 + lane] = hn;
            }
        }
        __syncthreads();
        // step B: row r, t+1 -> t+2, K-split over 4 waves
        if (tid < 48) {
            shxB[tid] = bf2f(lhalf_bf[((size_t)(t + 1) * 960 + r) * 48 + tid]);
            shxB[96 + tid] = h1[r * 48 + tid];
        }
        __syncthreads();
        float acc = 0.f;
        u64 m2 = maskB;
        for (int e = 0; e < neB; ++e) {
            int b = __ffsll((long long)m2) - 1;
            m2 &= m2 - 1;
            u32 en = entB[e];
            int win = (en >> 8) & 0xff;
            float cinv = 1.f / (float)(en & 0xff);
            const u32* wp = wscf_p + (b * 24 + wv * 6) * 48 + lo;
            const float* xv = h1 + win * 48 + wv * 12;
            float a = 0.f;
#pragma unroll
            for (int dp = 0; dp < 6; ++dp) {
                u32 u = wp[dp * 48];
                a += bflo(u) * xv[2 * dp] + bfhi(u) * xv[2 * dp + 1];
            }
            acc += a * cinv;
        }
        if (lane < 48) ps1[wv * 48 + lane] = acc;
        __syncthreads();
        if (wv == 0 && lane < 48) {
            float rh = ps1[lane] + ps1[48 + lane] + ps1[96 + lane] + ps1[144 + lane] +
                       biasL[192 + lane];
            shxB[48 + lane] = fmaxf(rh, 0.f);
        }
        __syncthreads();
        float aR = 0.f, aZ = 0.f, aI = 0.f, aH = 0.f;
        int dp0 = wv * 18;
#pragma unroll
        for (int i = 0; i < 18; ++i) {
            int dp = dp0 + i;
            u32 uR = Wr_p[dp * 48 + lo], uZ = Wz_p[dp * 48 + lo];
            float xlo = shxB[2 * dp], xhi = shxB[2 * dp + 1];
            aR += bflo(uR) * xlo + bfhi(uR) * xhi;
            aZ += bflo(uZ) * xlo + bfhi(uZ) * xhi;
            if (dp < 48) {
                u32 uI = Win_p[dp * 48 + lo];
                aI += bflo(uI) * xlo + bfhi(uI) * xhi;
            } else {
                u32 uH = Whn_p[(dp - 48) * 48 + lo];
                aH += bflo(uH) * xlo + bfhi(uH) * xhi;
            }
        }
        if (lane < 48) {
            ps2[(wv * 4 + 0) * 48 + lane] = aR;
            ps2[(wv * 4 + 1) * 48 + lane] = aZ;
            ps2[(wv * 4 + 2) * 48 + lane] = aI;
            ps2[(wv * 4 + 3) * 48 + lane] = aH;
        }
        __syncthreads();
        if (wv == 0) {
            float sv = scoreA;
            if (lane < 48) {
                float AR = 0.f, AZ = 0.f, AI = 0.f, AH = 0.f;
#pragma unroll
                for (int w2 = 0; w2 < 4; ++w2) {
                    AR += ps2[(w2 * 4 + 0) * 48 + lane];
                    AZ += ps2[(w2 * 4 + 1) * 48 + lane];
                    AI += ps2[(w2 * 4 + 2) * 48 + lane];
                    AH += ps2[(w2 * 4 + 3) * 48 + lane];
                }
                float hprev = shxB[96 + lane];
                float rr = sigmoidf_(AR + biasL[lane]);
                float zz = sigmoidf_(AZ + biasL[48 + lane]);
                float ng = tanhf(AI + biasL[96 + lane] + rr * (AH + biasL[144 + lane]));
                float hn = (1.0f - zz) * ng + zz * hprev;
                h0hist[(size_t)(t + 2) * 4608 + r * 48 + lane] = hn;
                if (t + 2 == TT) hfin[r * 48 + lane] = hn;
                sv += hn * scwL[lane];
            }
            for (int off = 32; off; off >>= 1) sv += __shfl_down(sv, off);
            if (lane == 0) score_acc[r] = (t == 0 ? 0.f : score_acc[r]) + sv;
        }
    } else if (bid < 312) {
        // rhalf for steps t-1 and t, straight from materialized h0hist
        float* smf = (float*)smem;
        const int widx = (bid - 96) * 4 + wv;  // 0..863
        const int row = 96 + widx;
        float* myw = smf + wv * 1728;
        for (int pass = 0; pass < 2; ++pass) {
            int ts = t - 1 + pass;
            if (ts < 0 || ts >= TT) continue;
            const float* hcur = h0hist + (size_t)ts * 4608;
            const u32* bp = binc + (size_t)(ts * 960 + row) * 20;
            u64 mask = ((u64)bp[1] << 32) | (u64)bp[0];
            int ne = __popcll(mask);
            const u16* ent = (const u16*)(bp + 2);
            for (int i = lane; i < ne * 48; i += 64) {
                int e = i / 48, c = i - e * 48;
                myw[i] = hcur[((ent[e] >> 8) & 0xff) * 48 + c];
            }
            __syncthreads();
            float acc = 0.f;
            u64 m2 = mask;
            for (int e = 0; e < ne; ++e) {
                int b = __ffsll((long long)m2) - 1;
                m2 &= m2 - 1;
                float cinv = 1.0f / (float)(ent[e] & 0xff);
                const u32* wp = wscf_p + b * 24 * 48 + lo;
                const float* xv = myw + e * 48;
                float a = 0.f;
#pragma unroll 8
                for (int dp = 0; dp < 24; ++dp) {
                    u32 u = wp[dp * 48];
                    a += bflo(u) * xv[2 * dp] + bfhi(u) * xv[2 * dp + 1];
                }
                acc += a * cinv;
            }
            float rh = fmaxf(acc + bias5[192 + lo], 0.f);
            if (lane < 48) rhalf_all[((size_t)ts * 864 + widx) * 48 + lane] = f2bf(rh);
            __syncthreads();
        }
    } else {
        // followers: steps s0 = t-4 and s0+1
        int s0 = t - 4;
        if (s0 < 0 || s0 >= TT) return;
        u32* sWr = (u32*)smem;                        // 3456
        u32* sWz = (u32*)(smem + 13824);              // 3456
        u32* sWin = (u32*)(smem + 27648);             // 2304
        u32* sx = (u32*)(smem + 36864) + wv * 48;     // 4x48
        float* shh = (float*)(smem + 37632) + wv * 48;// 4x48
        for (int i = tid; i < 3456; i += 256) { sWr[i] = Wr_p[i]; sWz[i] = Wz_p[i]; }
        for (int i = tid; i < 2304; i += 256) sWin[i] = Win_p[i];
        u32 whn[24];
#pragma unroll
        for (int dp = 0; dp < 24; ++dp) whn[dp] = Whn_p[dp * 48 + lo];
        const int widx = (bid - 312) * 4 + wv;  // 0..863
        const int row = 96 + widx;
        float hreg = (s0 == 0) ? hx[(row % 96) * 48 + lo] : hf[widx * 48 + lo];
        const float bRb = bias5[lo], bZb = bias5[48 + lo], bIb = bias5[96 + lo],
                    bHb = bias5[144 + lo];
        const float swv = (lane < 48) ? scw[lane] : 0.f;
        float score = 0.f;
        for (int ss = s0; ss < s0 + 2; ++ss) {
            if (lane < 24) {
                sx[lane] = *(const u32*)(lhalf_bf + ((size_t)ss * 960 + row) * 48 + 2 * lane);
                sx[24 + lane] =
                    *(const u32*)(rhalf_all + ((size_t)ss * 864 + widx) * 48 + 2 * lane);
            }
            if (lane < 48) shh[lane] = hreg;
            __syncthreads();
            float aR = 0.f, aZ = 0.f, aI = 0.f, aH = 0.f;
#pragma unroll 8
            for (int dp = 0; dp < 48; ++dp) {
                u32 xp = sx[dp];
                float xlo = bflo(xp), xhi = bfhi(xp);
                u32 uR = sWr[dp * 48 + lo], uZ = sWz[dp * 48 + lo], uI = sWin[dp * 48 + lo];
                aR += bflo(uR) * xlo + bfhi(uR) * xhi;
                aZ += bflo(uZ) * xlo + bfhi(uZ) * xhi;
                aI += bflo(uI) * xlo + bfhi(uI) * xhi;
            }
#pragma unroll 8
            for (int dp = 48; dp < 72; ++dp) {
                float xlo = shh[2 * dp - 96], xhi = shh[2 * dp - 95];
                u32 uR = sWr[dp * 48 + lo], uZ = sWz[dp * 48 + lo], uH = whn[dp - 48];
                aR += bflo(uR) * xlo + bfhi(uR) * xhi;
                aZ += bflo(uZ) * xlo + bfhi(uZ) * xhi;
                aH += bflo(uH) * xlo + bfhi(uH) * xhi;
            }
            float rr = sigmoidf_(aR + bRb);
            float zz = sigmoidf_(aZ + bZb);
            float ng = tanhf(aI + bIb + rr * (aH + bHb));
            hreg = (1.0f - zz) * ng + zz * hreg;
            score += hreg * swv;
            __syncthreads();
        }
        if (lane < 48) {
            hf[widx * 48 + lane] = hreg;
            if (s0 + 1 == TT - 1) hfin[(size_t)row * 48 + lane] = hreg;
        }
        for (int off = 32; off; off >>= 1) score += __shfl_down(score, off);
        if (lane == 0) score_acc[row] = (s0 == 0 ? 0.f : score_acc[row]) + score;
    }
}

// ---------------- epilogue ----------------
__global__ void final_k(const float* __restrict__ hlast, const float* __restrict__ score_acc,
                        const float* __restrict__ dyw, const float* __restrict__ dyb,
                        const float* __restrict__ scoreb, float* __restrict__ out) {
    int row = blockIdx.x, lane = threadIdx.x;
    int n = row % 96, k = row / 96;
    __shared__ float sh_h[48];
    if (lane < 48) sh_h[lane] = hlast[row * 48 + lane];
    __syncthreads();
    if (lane < 80) {
        float a = dyb[lane];
#pragma unroll 8
        for (int d = 0; d < 48; d++) a += sh_h[d] * dyw[lane * 48 + d];
        a = fmaxf(a, 0.0f);
        int j = lane / 40, tt = lane % 40;
        out[((k * TT + tt) * NN + n) * 2 + j] = a;
    } else if (lane == 80) {
        out[76800 + row] = score_acc[row] + 40.0f * scoreb[0];
    }
}

extern "C" void kernel_launch(void* const* d_in, const int* in_sizes, int n_in,
                              void* d_out, int out_size, void* d_ws, size_t ws_size,
                              hipStream_t stream) {
    const float* hx  = (const float*)d_in[0];
    const float* cur = (const float*)d_in[1];
    const float* yp  = (const float*)d_in[2];
    const float* img = (const float*)d_in[3];
    const float* c1w = (const float*)d_in[4];
    const float* c1b = (const float*)d_in[5];
    const float* c2w = (const float*)d_in[6];
    const float* c2b = (const float*)d_in[7];
    const float* vw  = (const float*)d_in[8];
    const float* vb  = (const float*)d_in[9];
    const float* wih = (const float*)d_in[10];
    const float* whh = (const float*)d_in[11];
    const float* bih = (const float*)d_in[12];
    const float* bhh = (const float*)d_in[13];
    const float* scfw = (const float*)d_in[14];
    const float* scfb = (const float*)d_in[15];
    const float* scw  = (const float*)d_in[16];
    const float* scb  = (const float*)d_in[17];
    const float* dyw  = (const float*)d_in[18];
    const float* dyb  = (const float*)d_in[19];
    float* out = (float*)d_out;

    char* ws = (char*)d_ws;  // ws_size ~268MB; no aliasing needed
    float* fmap1    = (float*)(ws + 0);          //   409,600
    float* fmap     = (float*)(ws + 409600);     //   819,200 -> 1228800
    u32*   binc     = (u32*)(ws + 1228800);      // 3,072,000 -> 4300800
    u16*   rhalf_all= (u16*)(ws + 4300800);      // 3,317,760 -> 7618560
    u16*   lhalf_bf = (u16*)(ws + 7618560);      // 3,686,400 -> 11304960
    float* h0hist   = (float*)(ws + 11304960);   //   755,712 -> 12060672
    float* hfin     = (float*)(ws + 12060672);   //   184,320 -> 12244992
    float* score_acc= (float*)(ws + 12244992);   //     3,840 -> 12248832
    u32*   wscf_p   = (u32*)(ws + 12248832);     //   165,888 -> 12414720
    u32*   Wr_p     = (u32*)(ws + 12414720);     //    13,824 -> 12428544
    u32*   Wz_p     = (u32*)(ws + 12428544);     //    13,824 -> 12442368
    u32*   Win_p    = (u32*)(ws + 12442368);     //     9,216 -> 12451584
    u32*   Whn_p    = (u32*)(ws + 12451584);     //     4,608 -> 12456192
    float* bias5    = (float*)(ws + 12456192);   //       960 -> 12457152
    float* hf       = (float*)(ws + 12457152);   //   165,888 -> 12623040

    conv1_t<<<100, 256, 0, stream>>>(img, c1w, c1b, fmap1);
    conv2_t<<<100, 256, 0, stream>>>(fmap1, c2w, c2b, fmap);
    pre_k<<<222 + 9600 + 400, 256, 0, stream>>>(scfw, wih, whh, bih, bhh, scfb, hx,
                                                h0hist, wscf_p, Wr_p, Wz_p, Win_p, Whn_p,
                                                bias5, yp, cur, fmap, vw, vb, lhalf_bf,
                                                binc);

    for (int t = 0; t <= 42; t += 2) {
        step2_k<<<528, 256, 0, stream>>>(t, h0hist, lhalf_bf, binc, wscf_p, Wr_p, Wz_p,
                                         Win_p, Whn_p, bias5, scw, score_acc, hfin,
                                         rhalf_all, hx, hf);
    }
    final_k<<<960, 128, 0, stream>>>(hfin, score_acc, dyw, dyb, scb, out);
}

// Round 15
// 489.385 us; speedup vs baseline: 2.9985x; 1.5834x over previous
//
#include <hip/hip_runtime.h>
#include <math.h>

#define KK 10
#define NN 96
#define TT 40

#define HZf 10.0f
#define R0f 0.5f
#define R1f 4.0f
#define RSTEPf ((4.0f - 0.5f) / 6.0f)
#define TWO_PIf 6.2831853071795864769f
#define TSTEPf (6.2831853071795864769f / 6.0f)

typedef unsigned short u16;
typedef unsigned int u32;
typedef unsigned long long u64;
typedef float f32x4 __attribute__((ext_vector_type(4)));

__device__ __forceinline__ u16 f2bf(float f) {
    union { float f; unsigned u; } v; v.f = f;
    unsigned r = v.u + 0x7fffu + ((v.u >> 16) & 1u);
    return (u16)(r >> 16);
}
__device__ __forceinline__ float bflo(u32 u) {
    union { unsigned u; float f; } v; v.u = u << 16; return v.f;
}
__device__ __forceinline__ float bfhi(u32 u) {
    union { unsigned u; float f; } v; v.u = u & 0xffff0000u; return v.f;
}
__device__ __forceinline__ float bf2f(u16 h) {
    union { unsigned u; float f; } v; v.u = ((unsigned)h) << 16; return v.f;
}
__device__ __forceinline__ float sigmoidf_(float x) { return 1.0f / (1.0f + expf(-x)); }

// ---------------- conv1 tiled: (4,160,160) -> relu -> (16,80,80), s2 p2 ----------------
__global__ __launch_bounds__(256) void conv1_t(const float* __restrict__ img,
                                               const float* __restrict__ w,
                                               const float* __restrict__ b,
                                               float* __restrict__ out) {
    __shared__ float sW[1600];
    __shared__ float sIn[1444];
    const int tid = threadIdx.x;
    const int bx = blockIdx.x % 10, by = blockIdx.x / 10;
    const int x0 = bx * 8, y0 = by * 8;
    for (int i = tid; i < 1600; i += 256) {
        int oc = i & 15, t2 = i >> 4, tap = t2 % 25, ic = t2 / 25;
        sW[i] = w[(oc * 4 + ic) * 25 + tap];
    }
    for (int i = tid; i < 1444; i += 256) {
        int ic = i / 361, rem = i % 361, r = rem / 19, c = rem % 19;
        int gy = 2 * y0 - 2 + r, gx = 2 * x0 - 2 + c;
        sIn[i] = (gy >= 0 && gy < 160 && gx >= 0 && gx < 160)
                     ? img[(ic * 160 + gy) * 160 + gx] : 0.f;
    }
    __syncthreads();
    const int pix = tid & 63, ocg = tid >> 6;
    const int px = pix & 7, py = pix >> 3;
    float acc[4];
#pragma unroll
    for (int j = 0; j < 4; ++j) acc[j] = b[ocg * 4 + j];
#pragma unroll
    for (int ic = 0; ic < 4; ++ic) {
        int ibase = ic * 361;
#pragma unroll
        for (int ky = 0; ky < 5; ++ky)
#pragma unroll
            for (int kx = 0; kx < 5; ++kx) {
                float iv = sIn[ibase + (2 * py + ky) * 19 + 2 * px + kx];
                f32x4 wv = *(const f32x4*)&sW[(ic * 25 + ky * 5 + kx) * 16 + ocg * 4];
#pragma unroll
                for (int j = 0; j < 4; ++j) acc[j] += iv * wv[j];
            }
    }
#pragma unroll
    for (int j = 0; j < 4; ++j)
        out[((ocg * 4 + j) * 80 + y0 + py) * 80 + x0 + px] = fmaxf(acc[j], 0.f);
}

// ---------------- conv2 tiled: (16,80,80) -> relu -> (32,80,80), s1 p2 ----------------
__global__ __launch_bounds__(256) void conv2_t(const float* __restrict__ in,
                                               const float* __restrict__ w,
                                               const float* __restrict__ b,
                                               float* __restrict__ out) {
    __shared__ float sW[12800];
    __shared__ float sIn[2304];
    const int tid = threadIdx.x;
    const int bx = blockIdx.x % 10, by = blockIdx.x / 10;
    const int x0 = bx * 8, y0 = by * 8;
    for (int i = tid; i < 12800; i += 256) {
        int oc = i & 31, t2 = i >> 5, tap = t2 % 25, ic = t2 / 25;
        sW[i] = w[(oc * 16 + ic) * 25 + tap];
    }
    for (int i = tid; i < 2304; i += 256) {
        int ic = i / 144, rem = i % 144, r = rem / 12, c = rem % 12;
        int gy = y0 - 2 + r, gx = x0 - 2 + c;
        sIn[i] = (gy >= 0 && gy < 80 && gx >= 0 && gx < 80)
                     ? in[(ic * 80 + gy) * 80 + gx] : 0.f;
    }
    __syncthreads();
    const int pix = tid & 63, ocg = tid >> 6;
    const int px = pix & 7, py = pix >> 3;
    float acc[8];
#pragma unroll
    for (int j = 0; j < 8; ++j) acc[j] = b[ocg * 8 + j];
    for (int ic = 0; ic < 16; ++ic) {
        int ibase = ic * 144;
#pragma unroll
        for (int ky = 0; ky < 5; ++ky)
#pragma unroll
            for (int kx = 0; kx < 5; ++kx) {
                float iv = sIn[ibase + (py + ky) * 12 + px + kx];
                int wb = (ic * 25 + ky * 5 + kx) * 32 + ocg * 8;
                f32x4 w0 = *(const f32x4*)&sW[wb];
                f32x4 w1 = *(const f32x4*)&sW[wb + 4];
#pragma unroll
                for (int j = 0; j < 4; ++j) { acc[j] += iv * w0[j]; acc[4 + j] += iv * w1[j]; }
            }
    }
#pragma unroll
    for (int j = 0; j < 8; ++j)
        out[((ocg * 8 + j) * 80 + y0 + py) * 80 + x0 + px] = fmaxf(acc[j], 0.f);
}

// ---------------- weight prep (+ h0 init folded in) ----------------
__global__ void prep_w3(const float* __restrict__ scf, const float* __restrict__ wih,
                        const float* __restrict__ whh, const float* __restrict__ bih,
                        const float* __restrict__ bhh, const float* __restrict__ scfb,
                        const float* __restrict__ hx, float* __restrict__ h0hist,
                        u32* __restrict__ wscf_p, u32* __restrict__ Wr_p,
                        u32* __restrict__ Wz_p, u32* __restrict__ Win_p,
                        u32* __restrict__ Whn_p, float* __restrict__ bias5) {
    int idx = blockIdx.x * blockDim.x + threadIdx.x;
    if (idx < 41472) {
        int o = idx % 48, dp = (idx / 48) % 24, b = idx / 1152;
        float v0 = scf[o * 1728 + b * 48 + 2 * dp];
        float v1 = scf[o * 1728 + b * 48 + 2 * dp + 1];
        wscf_p[idx] = (u32)f2bf(v0) | ((u32)f2bf(v1) << 16);
    } else if (idx < 44928) {
        int j = idx - 41472, od = j % 48, dp = j / 48;
        int kk0 = 2 * dp, kk1 = 2 * dp + 1;
        float v0 = kk0 < 96 ? wih[od * 96 + kk0] : whh[od * 48 + kk0 - 96];
        float v1 = kk1 < 96 ? wih[od * 96 + kk1] : whh[od * 48 + kk1 - 96];
        Wr_p[j] = (u32)f2bf(v0) | ((u32)f2bf(v1) << 16);
    } else if (idx < 48384) {
        int j = idx - 44928, od = j % 48, dp = j / 48;
        int row = 48 + od, kk0 = 2 * dp, kk1 = 2 * dp + 1;
        float v0 = kk0 < 96 ? wih[row * 96 + kk0] : whh[row * 48 + kk0 - 96];
        float v1 = kk1 < 96 ? wih[row * 96 + kk1] : whh[row * 48 + kk1 - 96];
        Wz_p[j] = (u32)f2bf(v0) | ((u32)f2bf(v1) << 16);
    } else if (idx < 50688) {
        int j = idx - 48384, od = j % 48, dp = j / 48;
        int row = 96 + od;
        Win_p[j] = (u32)f2bf(wih[row * 96 + 2 * dp]) | ((u32)f2bf(wih[row * 96 + 2 * dp + 1]) << 16);
    } else if (idx < 51840) {
        int j = idx - 50688, od = j % 48, dp = j / 48;
        int row = 96 + od;
        Whn_p[j] = (u32)f2bf(whh[row * 48 + 2 * dp]) | ((u32)f2bf(whh[row * 48 + 2 * dp + 1]) << 16);
    } else if (idx < 52080) {
        int j = idx - 51840, od = j % 48, q = j / 48;
        float v;
        if (q == 0) v = bih[od] + bhh[od];
        else if (q == 1) v = bih[48 + od] + bhh[48 + od];
        else if (q == 2) v = bih[96 + od];
        else if (q == 3) v = bhh[96 + od];
        else v = scfb[od];
        bias5[j] = v;
    } else if (idx < 56688) {
        int j = idx - 52080;
        h0hist[j] = hx[j];
    }
}

// ---------------- lhalf (bf16), 4 items per 256-thread block ----------------
__global__ __launch_bounds__(256) void lhalf_k(const float* __restrict__ yp,
                                               const float* __restrict__ cur,
                                               const float* __restrict__ fmap,
                                               const float* __restrict__ vw,
                                               const float* __restrict__ vb,
                                               u16* __restrict__ lhalf_bf) {
    int item = blockIdx.x * 4 + (threadIdx.x >> 6);  // t*960 + k*96 + n
    int lane = threadIdx.x & 63;
    int n = item % NN, k = (item / NN) % KK, t = item / (KK * NN);
    float lx = yp[((k * TT + t) * NN + n) * 2 + 0];
    float ly = yp[((k * TT + t) * NN + n) * 2 + 1];
    float px, py;
    if (t == 0) { px = cur[n * 2]; py = cur[n * 2 + 1]; }
    else { px = yp[((k * TT + t - 1) * NN + n) * 2]; py = yp[((k * TT + t - 1) * NN + n) * 2 + 1]; }
    float vx = (lx - px) * HZf, vy = (ly - py) * HZf;
    int ui = 40 - (int)ly;
    int vi = 40 - (int)lx;
    ui = min(max(ui, 0), 79);
    vi = min(max(vi, 0), 79);
    int row = k * NN + n;
    u16* dst = lhalf_bf + ((size_t)t * 960 + row) * 48;
    if (lane < 32) {
        dst[lane] = f2bf(fmap[(lane * 80 + ui) * 80 + vi]);
    } else if (lane < 48) {
        int f = lane - 32;
        float a = vb[f] + vx * vw[f * 2 + 0] + vy * vw[f * 2 + 1];
        dst[lane] = f2bf(fmaxf(a, 0.0f));
    }
}

// ---------------- bins: compact 80B/row-step: u64 mask + u16 entries (w<<8|c) ----------------
__global__ __launch_bounds__(256) void bins4_k(const float* __restrict__ yp,
                                               u32* __restrict__ binc) {
    int tk = blockIdx.x;  // t*10 + k
    int k = tk % KK, t = tk / KK;
    int tid = threadIdx.x;
    __shared__ float xs[96], ys[96];
    __shared__ int win_s[96 * 36];
    __shared__ int cnt_s[96 * 36];
    if (tid < 96) {
        xs[tid] = yp[((k * TT + t) * NN + tid) * 2 + 0];
        ys[tid] = yp[((k * TT + t) * NN + tid) * 2 + 1];
    }
    for (int i = tid; i < 96 * 36; i += 256) { win_s[i] = -1; cnt_s[i] = 0; }
    __syncthreads();
    for (int p = tid; p < 96 * 96; p += 256) {
        int i = p / 96, j = p % 96;
        if (i == j) continue;
        float dx = xs[j] - xs[i], dy = ys[j] - ys[i];
        float dist = sqrtf(dx * dx + dy * dy);
        if (dist < R0f || dist > R1f) continue;
        float dsafe = fmaxf(dist, 1e-10f);
        float cost = fminf(fmaxf(dx / dsafe, -1.0f), 1.0f);
        float ac = acosf(cost);
        float theta = (dy < 0.0f) ? (TWO_PIf - ac) : ac;
        int ub = (int)((dist - R0f) / RSTEPf); ub = min(max(ub, 0), 5);
        int vb = (int)(theta / TSTEPf);        vb = min(max(vb, 0), 5);
        int b = ub * 6 + vb;
        atomicAdd(&cnt_s[i * 36 + b], 1);
        atomicMax(&win_s[i * 36 + b], j);
    }
    __syncthreads();
    if (tid < 96) {
        u32 base = (u32)(t * 960 + k * 96 + tid) * 20u;
        u16* entg = (u16*)(binc + base + 2);
        u64 mask = 0ull;
        int ne = 0;
        for (int b = 0; b < 36; ++b) {
            int w = win_s[tid * 36 + b];
            if (w >= 0) {
                mask |= 1ull << b;
                entg[ne++] = (u16)((w << 8) | cnt_s[tid * 36 + b]);
            }
        }
        binc[base] = (u32)mask;
        binc[base + 1] = (u32)(mask >> 32);
    }
}

// ---------------- merged step launch ----------------
// blocks 0..95   : chain row t -> t+1           (requires t < 40)
// blocks 96..311 : rhalf_all[t] piggyback       (requires t < 40)
// blocks 312..527: follower GRU step s = t-1    (requires 1 <= t <= 40)
__global__ __launch_bounds__(256) void step_k(
    int t, float* __restrict__ h0hist, const u16* __restrict__ lhalf_bf,
    const u32* __restrict__ binc, const u32* __restrict__ wscf_p,
    const u32* __restrict__ Wr_p, const u32* __restrict__ Wz_p,
    const u32* __restrict__ Win_p, const u32* __restrict__ Whn_p,
    const float* __restrict__ bias5, const float* __restrict__ scw,
    float* __restrict__ score_acc, float* __restrict__ hfin,
    u16* __restrict__ rhalf_all, const float* __restrict__ hx,
    float* __restrict__ hf) {
    __shared__ u32 smu[9856];  // 39424 B, shared across the three roles
    float* smf = (float*)smu;
    const int tid = threadIdx.x;
    const int wv = tid >> 6, lane = tid & 63;
    const int lo = lane < 48 ? lane : 47;

    if (blockIdx.x < 96) {
        if (t >= TT) return;
        const float* hcur = h0hist + (size_t)t * 4608;
        const int r = blockIdx.x;
        float* shw = smf;                    // 1728
        float* shx = smf + 1728;             // 144  [lh|rh|h]
        float* ps1 = smf + 1872;             // 192  [4][48]
        float* ps2 = smf + 2064;             // 768  [4][4][48]
        u32* sent = (u32*)(smf + 2832);      // 20
        unsigned char* blist = (unsigned char*)(smf + 2852);  // 36

        if (tid < 20) sent[tid] = binc[(size_t)(t * 960 + r) * 20 + tid];
        if (tid < 48) {
            shx[tid] = bf2f(lhalf_bf[((size_t)t * 960 + r) * 48 + tid]);
            shx[96 + tid] = hcur[r * 48 + tid];
        }
        __syncthreads();
        u64 mask = ((u64)sent[1] << 32) | sent[0];
        int ne = __popcll(mask);
        const u16* ent = (const u16*)(sent + 2);
        if (tid < 36 && ((mask >> tid) & 1)) {
            int rank = __popcll(mask & ((1ull << tid) - 1ull));
            blist[rank] = (unsigned char)tid;
        }
        for (int i = tid; i < ne * 48; i += 256) {
            int e = i / 48, c = i - e * 48;
            int w = (ent[e] >> 8) & 0xff;
            shw[i] = hcur[w * 48 + c];
        }
        __syncthreads();
        // phase1: rhalf, wave wv covers dp [6wv, 6wv+6)
        float acc = 0.f;
        for (int e = 0; e < ne; ++e) {
            int b = blist[e];
            float cinv = 1.0f / (float)(ent[e] & 0xff);
            const u32* wp = wscf_p + (b * 24 + wv * 6) * 48 + lo;
            const float* xv = shw + e * 48 + wv * 12;
            float a = 0.f;
#pragma unroll
            for (int dp = 0; dp < 6; ++dp) {
                u32 u = wp[dp * 48];
                a += bflo(u) * xv[2 * dp] + bfhi(u) * xv[2 * dp + 1];
            }
            acc += a * cinv;
        }
        if (lane < 48) ps1[wv * 48 + lane] = acc;
        __syncthreads();
        if (wv == 0 && lane < 48) {
            float rh = ps1[lane] + ps1[48 + lane] + ps1[96 + lane] + ps1[144 + lane] +
                       bias5[192 + lane];
            shx[48 + lane] = fmaxf(rh, 0.f);
        }
        __syncthreads();
        // phase2: gates, wave wv covers dp [18wv, 18wv+18)
        float aR = 0.f, aZ = 0.f, aI = 0.f, aH = 0.f;
        int dp0 = wv * 18;
#pragma unroll
        for (int i = 0; i < 18; ++i) {
            int dp = dp0 + i;
            u32 uR = Wr_p[dp * 48 + lo], uZ = Wz_p[dp * 48 + lo];
            float xlo = shx[2 * dp], xhi = shx[2 * dp + 1];
            aR += bflo(uR) * xlo + bfhi(uR) * xhi;
            aZ += bflo(uZ) * xlo + bfhi(uZ) * xhi;
            if (dp < 48) {
                u32 uI = Win_p[dp * 48 + lo];
                aI += bflo(uI) * xlo + bfhi(uI) * xhi;
            } else {
                u32 uH = Whn_p[(dp - 48) * 48 + lo];
                aH += bflo(uH) * xlo + bfhi(uH) * xhi;
            }
        }
        if (lane < 48) {
            ps2[(wv * 4 + 0) * 48 + lane] = aR;
            ps2[(wv * 4 + 1) * 48 + lane] = aZ;
            ps2[(wv * 4 + 2) * 48 + lane] = aI;
            ps2[(wv * 4 + 3) * 48 + lane] = aH;
        }
        __syncthreads();
        if (wv == 0) {
            float sv = 0.f;
            if (lane < 48) {
                float AR = 0.f, AZ = 0.f, AI = 0.f, AH = 0.f;
#pragma unroll
                for (int w2 = 0; w2 < 4; ++w2) {
                    AR += ps2[(w2 * 4 + 0) * 48 + lane];
                    AZ += ps2[(w2 * 4 + 1) * 48 + lane];
                    AI += ps2[(w2 * 4 + 2) * 48 + lane];
                    AH += ps2[(w2 * 4 + 3) * 48 + lane];
                }
                float hprev = shx[96 + lane];
                float rr = sigmoidf_(AR + bias5[lane]);
                float zz = sigmoidf_(AZ + bias5[48 + lane]);
                float ng = tanhf(AI + bias5[96 + lane] + rr * (AH + bias5[144 + lane]));
                float hn = (1.0f - zz) * ng + zz * hprev;
                h0hist[(size_t)(t + 1) * 4608 + r * 48 + lane] = hn;
                if (t == TT - 1) hfin[r * 48 + lane] = hn;
                sv = hn * scw[lane];
            }
            for (int off = 32; off; off >>= 1) sv += __shfl_down(sv, off);
            if (lane == 0) score_acc[r] = (t == 0 ? 0.f : score_acc[r]) + sv;
        }
    } else if (blockIdx.x < 312) {
        if (t >= TT) return;
        const float* hcur = h0hist + (size_t)t * 4608;
        // rhalf piggyback: wave = one follower row
        int widx = (blockIdx.x - 96) * 4 + wv;  // 0..863
        int row = 96 + widx;
        float* myw = smf + wv * 1728;
        const u32* bp = binc + (size_t)(t * 960 + row) * 20;
        u64 mask = ((u64)bp[1] << 32) | bp[0];
        int ne = __popcll(mask);
        const u16* ent = (const u16*)(bp + 2);
        for (int i = lane; i < ne * 48; i += 64) {
            int e = i / 48, c = i - e * 48;
            int w = (ent[e] >> 8) & 0xff;
            myw[i] = hcur[w * 48 + c];
        }
        __syncthreads();
        float acc = 0.f;
        u64 m2 = mask;
        for (int e = 0; e < ne; ++e) {
            int b = __ffsll((long long)m2) - 1;
            m2 &= m2 - 1;
            float cinv = 1.0f / (float)(ent[e] & 0xff);
            const u32* wp = wscf_p + b * 24 * 48 + lo;
            const float* xv = myw + e * 48;
            float a = 0.f;
#pragma unroll 8
            for (int dp = 0; dp < 24; ++dp) {
                u32 u = wp[dp * 48];
                a += bflo(u) * xv[2 * dp] + bfhi(u) * xv[2 * dp + 1];
            }
            acc += a * cinv;
        }
        float rh = fmaxf(acc + bias5[192 + lo], 0.f);
        if (lane < 48) rhalf_all[((size_t)t * 864 + widx) * 48 + lane] = f2bf(rh);
    } else {
        // follower GRU step s = t-1
        int s = t - 1;
        if (s < 0 || s >= TT) return;
        u32* sWr = smu;            // 3456
        u32* sWz = smu + 3456;     // 3456
        u32* sWin = smu + 6912;    // 2304
        u32* sx = smu + 9216 + wv * 48;          // 4x48
        float* shh = (float*)(smu + 9408) + wv * 48;  // 4x48
        for (int i = tid; i < 3456; i += 256) { sWr[i] = Wr_p[i]; sWz[i] = Wz_p[i]; }
        for (int i = tid; i < 2304; i += 256) sWin[i] = Win_p[i];
        u32 whn[24];
#pragma unroll
        for (int dp = 0; dp < 24; ++dp) whn[dp] = Whn_p[dp * 48 + lo];
        int widx = (blockIdx.x - 312) * 4 + wv;  // 0..863
        int row = 96 + widx;
        const float* hsrc = (s == 0) ? (hx + (row % 96) * 48) : (hf + (s & 1) * 41472 + widx * 48);
        float hreg = hsrc[lo];
        if (lane < 24) {
            sx[lane] = *(const u32*)(lhalf_bf + ((size_t)s * 960 + row) * 48 + 2 * lane);
            sx[24 + lane] = *(const u32*)(rhalf_all + ((size_t)s * 864 + widx) * 48 + 2 * lane);
        }
        if (lane < 48) shh[lane] = hreg;
        __syncthreads();
        const float bRb = bias5[lo], bZb = bias5[48 + lo], bIb = bias5[96 + lo],
                    bHb = bias5[144 + lo];
        float aR = 0.f, aZ = 0.f, aI = 0.f, aH = 0.f;
#pragma unroll 8
        for (int dp = 0; dp < 48; ++dp) {
            u32 xp = sx[dp];
            float xlo = bflo(xp), xhi = bfhi(xp);
            u32 uR = sWr[dp * 48 + lo], uZ = sWz[dp * 48 + lo], uI = sWin[dp * 48 + lo];
            aR += bflo(uR) * xlo + bfhi(uR) * xhi;
            aZ += bflo(uZ) * xlo + bfhi(uZ) * xhi;
            aI += bflo(uI) * xlo + bfhi(uI) * xhi;
        }
#pragma unroll 8
        for (int dp = 48; dp < 72; ++dp) {
            float xlo = shh[2 * dp - 96], xhi = shh[2 * dp - 95];
            u32 uR = sWr[dp * 48 + lo], uZ = sWz[dp * 48 + lo], uH = whn[dp - 48];
            aR += bflo(uR) * xlo + bfhi(uR) * xhi;
            aZ += bflo(uZ) * xlo + bfhi(uZ) * xhi;
            aH += bflo(uH) * xlo + bfhi(uH) * xhi;
        }
        float rr = sigmoidf_(aR + bRb);
        float zz = sigmoidf_(aZ + bZb);
        float ng = tanhf(aI + bIb + rr * (aH + bHb));
        float hn = (1.0f - zz) * ng + zz * hreg;
        if (lane < 48) {
            hf[((s + 1) & 1) * 41472 + widx * 48 + lane] = hn;
            if (s == TT - 1) hfin[(size_t)row * 48 + lane] = hn;
        }
        float sv = (lane < 48) ? hn * scw[lane] : 0.f;
        for (int off = 32; off; off >>= 1) sv += __shfl_down(sv, off);
        if (lane == 0) score_acc[row] = (s == 0 ? 0.f : score_acc[row]) + sv;
    }
}

// ---------------- epilogue ----------------
__global__ void final_k(const float* __restrict__ hlast, const float* __restrict__ score_acc,
                        const float* __restrict__ dyw, const float* __restrict__ dyb,
                        const float* __restrict__ scoreb, float* __restrict__ out) {
    int row = blockIdx.x, lane = threadIdx.x;
    int n = row % 96, k = row / 96;
    __shared__ float sh_h[48];
    if (lane < 48) sh_h[lane] = hlast[row * 48 + lane];
    __syncthreads();
    if (lane < 80) {
        float a = dyb[lane];
#pragma unroll 8
        for (int d = 0; d < 48; d++) a += sh_h[d] * dyw[lane * 48 + d];
        a = fmaxf(a, 0.0f);
        int j = lane / 40, tt = lane % 40;
        out[((k * TT + tt) * NN + n) * 2 + j] = a;
    } else if (lane == 80) {
        out[76800 + row] = score_acc[row] + 40.0f * scoreb[0];
    }
}

extern "C" void kernel_launch(void* const* d_in, const int* in_sizes, int n_in,
                              void* d_out, int out_size, void* d_ws, size_t ws_size,
                              hipStream_t stream) {
    const float* hx  = (const float*)d_in[0];
    const float* cur = (const float*)d_in[1];
    const float* yp  = (const float*)d_in[2];
    const float* img = (const float*)d_in[3];
    const float* c1w = (const float*)d_in[4];
    const float* c1b = (const float*)d_in[5];
    const float* c2w = (const float*)d_in[6];
    const float* c2b = (const float*)d_in[7];
    const float* vw  = (const float*)d_in[8];
    const float* vb  = (const float*)d_in[9];
    const float* wih = (const float*)d_in[10];
    const float* whh = (const float*)d_in[11];
    const float* bih = (const float*)d_in[12];
    const float* bhh = (const float*)d_in[13];
    const float* scfw = (const float*)d_in[14];
    const float* scfb = (const float*)d_in[15];
    const float* scw  = (const float*)d_in[16];
    const float* scb  = (const float*)d_in[17];
    const float* dyw  = (const float*)d_in[18];
    const float* dyb  = (const float*)d_in[19];
    float* out = (float*)d_out;

    char* ws = (char*)d_ws;
    // fmap1/fmap alias the front of binc (dead after lhalf_k; bins4_k runs after).
    u32*   binc     = (u32*)(ws + 0);           // 3,072,000 -> 3072000
    float* fmap1    = (float*)(ws + 0);         //   409,600 (dead after conv2)
    float* fmap     = (float*)(ws + 409600);    //   819,200 (dead after lhalf_k)
    u16*   rhalf_all= (u16*)(ws + 3072000);     // 3,317,760 -> 6389760
    u16*   lhalf_bf = (u16*)(ws + 6389760);     // 3,686,400 -> 10076160
    float* h0hist   = (float*)(ws + 10076160);  //   755,712 -> 10831872
    float* hfin     = (float*)(ws + 10831872);  //   184,320 -> 11016192
    float* score_acc= (float*)(ws + 11016192);  //     3,840 -> 11020032
    u32*   wscf_p   = (u32*)(ws + 11020032);    //   165,888 -> 11185920
    u32*   Wr_p     = (u32*)(ws + 11185920);    //    13,824 -> 11199744
    u32*   Wz_p     = (u32*)(ws + 11199744);    //    13,824 -> 11213568
    u32*   Win_p    = (u32*)(ws + 11213568);    //     9,216 -> 11222784
    u32*   Whn_p    = (u32*)(ws + 11222784);    //     4,608 -> 11227392
    float* bias5    = (float*)(ws + 11227392);  //       960 -> 11228352
    float* hf       = (float*)(ws + 11228352);  //   331,776 -> 11560128 (2 x 864 x 48)

    conv1_t<<<100, 256, 0, stream>>>(img, c1w, c1b, fmap1);
    conv2_t<<<100, 256, 0, stream>>>(fmap1, c2w, c2b, fmap);
    prep_w3<<<222, 256, 0, stream>>>(scfw, wih, whh, bih, bhh, scfb, hx, h0hist,
                                     wscf_p, Wr_p, Wz_p, Win_p, Whn_p, bias5);
    lhalf_k<<<TT * KK * NN / 4, 256, 0, stream>>>(yp, cur, fmap, vw, vb, lhalf_bf);
    bins4_k<<<TT * KK, 256, 0, stream>>>(yp, binc);

    for (int t = 0; t <= TT; ++t) {
        step_k<<<528, 256, 0, stream>>>(t, h0hist, lhalf_bf, binc, wscf_p, Wr_p, Wz_p,
                                        Win_p, Whn_p, bias5, scw, score_acc, hfin,
                                        rhalf_all, hx, hf);
    }
    final_k<<<960, 128, 0, stream>>>(hfin, score_acc, dyw, dyb, scb, out);
}